// Round 1
// baseline (343.842 us; speedup 1.0000x reference)
//
#include <hip/hip_runtime.h>

#define HD   64
#define NB   4
#define PROJ 256   // HD * NB
#define NPB  32    // nodes per block in proj kernel

// xb layout: xb[n][o][b]  (o = output dim 0..63, b = basis 0..3)
__global__ __launch_bounds__(256) void proj_kernel(
    const float* __restrict__ f, const float* __restrict__ Vl,
    float* __restrict__ xb, int n_nodes) {
    int c = threadIdx.x;        // column in interleaved layout: c = o*4 + b
    int b = c & 3;
    int o = c >> 2;
    // this thread's weight column: V[b, :, o]
    float w[HD];
#pragma unroll
    for (int i = 0; i < HD; ++i) w[i] = Vl[((size_t)b * HD + i) * HD + o];

    __shared__ float fs[NPB * HD];
    int n0 = blockIdx.x * NPB;
#pragma unroll
    for (int k = 0; k < (NPB * HD) / 256; ++k) {
        int idx = k * 256 + c;
        int n = n0 + idx / HD;
        fs[idx] = (n < n_nodes) ? f[(size_t)n0 * HD + idx] : 0.f;
    }
    __syncthreads();

    int nmax = n_nodes - n0; if (nmax > NPB) nmax = NPB;
    for (int n = 0; n < nmax; ++n) {
        float acc = 0.f;
#pragma unroll
        for (int i = 0; i < HD; ++i) acc += fs[n * HD + i] * w[i];  // LDS broadcast
        xb[(size_t)(n0 + n) * PROJ + c] = acc;  // coalesced
    }
}

__global__ __launch_bounds__(256) void edge_kernel(
    const float* __restrict__ xb, const float* __restrict__ comp_l,
    const float* __restrict__ norm,
    const int* __restrict__ src, const int* __restrict__ dst,
    const int* __restrict__ etype,
    float* __restrict__ h, int n_edges) {
    int e = blockIdx.x * 4 + (threadIdx.x >> 6);
    if (e >= n_edges) return;
    int lane = threadIdx.x & 63;
    int s = src[e];
    int d = dst[e];
    int r = etype[e];
    float nrm = norm[e];
    float4 cf = *(const float4*)(comp_l + (size_t)r * NB);
    const float4* x = (const float4*)(xb + (size_t)s * PROJ);
    float4 v = x[lane];  // one coalesced 1KB load per wave
    float m = nrm * (cf.x * v.x + cf.y * v.y + cf.z * v.z + cf.w * v.w);
    atomicAdd(h + (size_t)d * HD + lane, m);
}

__global__ __launch_bounds__(256) void finish_kernel(
    const float* __restrict__ h, const float* __restrict__ f,
    const float* __restrict__ bias_l, float* __restrict__ out, int total) {
    int i = blockIdx.x * 256 + threadIdx.x;
    if (i >= total) return;
    float v = h[i] + bias_l[i & (HD - 1)];
    out[i] = fmaxf(v, 0.f) + f[i];
}

extern "C" void kernel_launch(void* const* d_in, const int* in_sizes, int n_in,
                              void* d_out, int out_size, void* d_ws, size_t ws_size,
                              hipStream_t stream) {
    const float* features = (const float*)d_in[0];
    const float* norm     = (const float*)d_in[1];
    const float* V        = (const float*)d_in[2];
    const float* comp     = (const float*)d_in[3];
    const float* bias     = (const float*)d_in[4];
    const int*   src      = (const int*)d_in[5];
    const int*   dst      = (const int*)d_in[6];
    const int*   etype    = (const int*)d_in[7];
    float* out = (float*)d_out;

    int n_nodes = in_sizes[0] / HD;
    int n_edges = in_sizes[5];
    int L       = in_sizes[2] / (NB * HD * HD);   // N_HID
    int l       = L - 1;                          // only the last layer survives
    int comp_stride = in_sizes[3] / L;            // NUM_RELS * NB

    const float* Vl     = V    + (size_t)l * NB * HD * HD;
    const float* comp_l = comp + (size_t)l * comp_stride;
    const float* bias_l = bias + (size_t)l * HD;

    float* xb = (float*)d_ws;                       // [n_nodes, 256]
    float* h  = xb + (size_t)n_nodes * PROJ;        // [n_nodes, 64]

    hipMemsetAsync(h, 0, (size_t)n_nodes * HD * sizeof(float), stream);

    proj_kernel<<<(n_nodes + NPB - 1) / NPB, 256, 0, stream>>>(features, Vl, xb, n_nodes);
    edge_kernel<<<(n_edges + 3) / 4, 256, 0, stream>>>(xb, comp_l, norm, src, dst, etype, h, n_edges);

    int total = n_nodes * HD;
    finish_kernel<<<(total + 255) / 256, 256, 0, stream>>>(h, features, bias_l, out, total);
}